// Round 9
// baseline (318.346 us; speedup 1.0000x reference)
//
#include <hip/hip_runtime.h>
#include <hip/hip_fp16.h>
#include <math.h>

typedef _Float16 half8 __attribute__((ext_vector_type(8)));
typedef __fp16 fp16x2 __attribute__((ext_vector_type(2)));
typedef float f32x4 __attribute__((ext_vector_type(4)));

#define BATCH 1024
#define IN_DIM 4096
#define HV 8192
#define NTAP 40          // 39 gates -> degree-39 polynomial -> 40 taps

#define BM 128
#define BN 128
#define BK 32
#define BKP 36           // f32 fallback LDS row stride

// fused gemm geometry (R5 tile, 2 LDS buffers)
#define BM2 128
#define BN2 256
#define BK2 64
#define NT2 (IN_DIM / BK2)       // 64 K-tiles
#define ASZ (BM2 * BK2)          // 8192 f16 (16 KB)
#define BSZ (BN2 * BK2)          // 16384 f16 (32 KB)
#define TSZ (ASZ + BSZ)          // 24576 f16 (48 KB) per buffer

#define GLD16(g, l) __builtin_amdgcn_global_load_lds(                          \
    (const __attribute__((address_space(1))) void*)(g),                        \
    (__attribute__((address_space(3))) void*)(l), 16, 0, 0)

// pack 8 f32 -> 8 f16 (RTZ), 4 VALU instrs (fallback path only)
static __device__ __forceinline__ half8 pk8(f32x4 a, f32x4 b) {
    union { fp16x2 p[4]; half8 h; } u;
    u.p[0] = __builtin_amdgcn_cvt_pkrtz(a.x, a.y);
    u.p[1] = __builtin_amdgcn_cvt_pkrtz(a.z, a.w);
    u.p[2] = __builtin_amdgcn_cvt_pkrtz(b.x, b.y);
    u.p[3] = __builtin_amdgcn_cvt_pkrtz(b.z, b.w);
    return u.h;
}

typedef _Float16 half4v __attribute__((ext_vector_type(4)));

// ---------------- prep: cvt x (f32->f16) + gate-polynomial taps, one launch ----------
__global__ __launch_bounds__(256) void prep(const float4* __restrict__ src,
                                            half4v* __restrict__ dst, int n4,
                                            const float* __restrict__ qp,
                                            float* __restrict__ taps) {
    int i = blockIdx.x * 256 + threadIdx.x;
    if (i < n4) {
        float4 v = src[i];
        half4v h;
        h.x = (_Float16)v.x; h.y = (_Float16)v.y;
        h.z = (_Float16)v.z; h.w = (_Float16)v.w;
        dst[i] = h;
    } else if (blockIdx.x == (unsigned)(n4 / 256) && threadIdx.x < 64) {
        // last (extra) block, wave 0: taps
        const int lane = threadIdx.x;
        float qv = (lane < 39) ? qp[lane] : 0.f;
        float pr = (lane == 0) ? 1.f : 0.f;
        float pim = 0.f;
        for (int t = 0; t < 39; t++) {
            float a = __shfl(qv, t, 64) * 0.5f;
            float c = cosf(a), s = sinf(a);
            float ur = __shfl_up(pr, 1, 64);
            float ui = __shfl_up(pim, 1, 64);
            if (lane == 0) { ur = 0.f; ui = 0.f; }
            float nr = c * pr - s * ui;
            float ni = c * pim + s * ur;
            pr = nr; pim = ni;
        }
        if (lane < NTAP) taps[lane] = pr;
    }
}

// ---------------- primary GEMM: fused W-conversion, 2-buffer counted-vmcnt pipeline ----
// 128(M) x 256(N) tile, BK=64, 512 threads = 8 waves (2M x 4N), 64x64 per wave.
// Grid 32x8 = 256 blocks = 1/CU.  LDS 2 x 48 KB.
// A (x, f16 via prep): GLD16 DMA staging (R5-proven).
// B (W): staged DIRECTLY from f32 via registers -- 2x dwordx4 load, RNE f16 casts,
//   ds_write_b128 into the same swizzled layout.  Eliminates the 30 us cvt_W pass.
// Per-iter schedule (one barrier/tile, counted vmcnt; in-order vmcnt retirement):
//   A_DMA(t+1 -> nxt)            [+2 vm]   (nxt freed by previous barrier)
//   COMPUTE(cur)                           (ds_read + MFMA)
//   CVT_WRITE(B(t+1) -> nxt)               (auto-wait vmcnt<=2 retires B-loads t+1)
//   B_LOAD(t+2)                  [+8 vm]
//   s_waitcnt vmcnt(8)                     (retires A-DMA t+1; 8 = B-loads t+2)
//   s_waitcnt lgkmcnt(0); s_barrier        (ds_writes visible; nxt ready)
// Hazards: A-region [0,ASZ) and B-region [ASZ,TSZ) disjoint; writes to nxt only after
// the barrier that freed it; all barriers uniform.
// LDS swizzle (verified, conflicts = 0): physical 16B slot s of row R holds chunk
// s^(R&7); A: GLD16 dest linear + inverse-swizzled source; B: ds_write to physical slot.
__global__ __launch_bounds__(512, 2) void gemm_fused(
        const _Float16* __restrict__ A,   // [BATCH][IN_DIM] f16 (x converted)
        const float*    __restrict__ W,   // [HV][IN_DIM] f32 (raw input)
        float* __restrict__ out,          // classical [BATCH][HV]
        long out_n) {
    __shared__ __align__(16) _Float16 lds[2 * TSZ];   // 96 KB

    const int tid  = threadIdx.x;
    const int lane = tid & 63;
    const int wave = tid >> 6;          // 0..7
    const int wm = wave & 1;            // 2 waves in M (64 rows each)
    const int wn = wave >> 1;           // 4 waves in N (64 cols each)
    const int q = lane >> 4, r = lane & 15;
    const int bm = blockIdx.y * BM2;
    const int bn = blockIdx.x * BN2;

    // ---- A staging (GLD16): 1024 chunks of 16B, thread covers p = h*512+tid ----
    const _Float16* srcA[2];
    int dA[2];
    #pragma unroll
    for (int h = 0; h < 2; h++) {
        const int p = h * 512 + tid;
        const int R = p >> 3, c = (p & 7) ^ (R & 7);
        srcA[h] = A + (size_t)(bm + R) * IN_DIM + c * 8;
        dA[h] = (h * 512 + wave * 64) * 8;           // wave-uniform; HW adds lane*16B
    }
    // ---- B staging (reg path from f32 W): 2048 chunks, thread covers 4 ----
    const float* srcBW[4];
    int dBo[4];
    #pragma unroll
    for (int h = 0; h < 4; h++) {
        const int p = h * 512 + tid;
        const int R = p >> 3, c = (p & 7) ^ (R & 7);
        srcBW[h] = W + (size_t)(bn + R) * IN_DIM + c * 8;   // 8 consecutive f32
        dBo[h] = ASZ + p * 8;                               // linear physical chunk
    }

    f32x4 acc[4][4] = {};
    f32x4 brg[8];                      // one in-flight B tile (32 f32)

#define A_DMA(u, k0)  do {                                   \
        _Float16* bpA = &lds[(u) * TSZ];                     \
        GLD16(srcA[0] + (k0), bpA + dA[0]);                  \
        GLD16(srcA[1] + (k0), bpA + dA[1]);                  \
    } while (0)

#define B_LOAD(k0)  do {                                     \
        _Pragma("unroll")                                    \
        for (int h = 0; h < 4; h++) {                        \
            brg[2*h]   = *(const f32x4*)(srcBW[h] + (k0));   \
            brg[2*h+1] = *(const f32x4*)(srcBW[h] + (k0) + 4); \
        }                                                    \
    } while (0)

#define CVT_WRITE(u)  do {                                   \
        _Float16* bpW = &lds[(u) * TSZ];                     \
        _Pragma("unroll")                                    \
        for (int h = 0; h < 4; h++) {                        \
            f32x4 lo = brg[2*h], hi = brg[2*h+1];            \
            half8 hv;                                        \
            hv[0] = (_Float16)lo.x; hv[1] = (_Float16)lo.y;  \
            hv[2] = (_Float16)lo.z; hv[3] = (_Float16)lo.w;  \
            hv[4] = (_Float16)hi.x; hv[5] = (_Float16)hi.y;  \
            hv[6] = (_Float16)hi.z; hv[7] = (_Float16)hi.w;  \
            *(half8*)&bpW[dBo[h]] = hv;                      \
        }                                                    \
    } while (0)

    // fragment LDS offsets: row R (stride 64 f16), logical slot s=kk*4+q,
    // physical slot s^(R&7) = s^(r&7) since 64|wm*64 and 16|i*16.
#define COMPUTE(u)  do {                                                            \
        const _Float16* bp = &lds[(u) * TSZ];                                       \
        half8 af[4][2], bf[4][2];                                                   \
        _Pragma("unroll")                                                           \
        for (int i = 0; i < 4; i++)                                                 \
            _Pragma("unroll")                                                       \
            for (int kk = 0; kk < 2; kk++) {                                        \
                const int R = wm * 64 + i * 16 + r;                                 \
                const int sw = (kk * 4 + q) ^ (r & 7);                              \
                af[i][kk] = *(const half8*)&bp[R * 64 + sw * 8];                    \
            }                                                                       \
        _Pragma("unroll")                                                           \
        for (int j = 0; j < 4; j++)                                                 \
            _Pragma("unroll")                                                       \
            for (int kk = 0; kk < 2; kk++) {                                        \
                const int R = wn * 64 + j * 16 + r;                                 \
                const int sw = (kk * 4 + q) ^ (r & 7);                              \
                bf[j][kk] = *(const half8*)&bp[ASZ + R * 64 + sw * 8];              \
            }                                                                       \
        __builtin_amdgcn_s_setprio(1);                                              \
        _Pragma("unroll")                                                           \
        for (int i = 0; i < 4; i++)                                                 \
            _Pragma("unroll")                                                       \
            for (int j = 0; j < 4; j++)                                             \
                _Pragma("unroll")                                                   \
                for (int kk = 0; kk < 2; kk++)                                      \
                    acc[i][j] = __builtin_amdgcn_mfma_f32_16x16x32_f16(             \
                        af[i][kk], bf[j][kk], acc[i][j], 0, 0, 0);                  \
        __builtin_amdgcn_s_setprio(0);                                              \
    } while (0)

    // ---- prologue: buf0 = tile 0; B(1) loads in flight ----
    B_LOAD(0);                 // [vm: B0=8]
    A_DMA(0, 0);               // [vm: B0=8, A0=2]
    CVT_WRITE(0);              // auto-wait retires B0
    B_LOAD(BK2);               // [vm: A0=2, B1=8]
    asm volatile("s_waitcnt vmcnt(8)" ::: "memory");     // A0 retired (older)
    asm volatile("s_waitcnt lgkmcnt(0)" ::: "memory");   // ds_writes visible
    __builtin_amdgcn_sched_barrier(0);
    __builtin_amdgcn_s_barrier();                        // buf0 ready for all waves

    int cur = 0;
    for (int t = 0; t < NT2; ++t) {
        const int nxt = cur ^ 1;
        if (t + 1 < NT2) A_DMA(nxt, (t + 1) * BK2);      // nxt freed by prev barrier
        COMPUTE(cur);
        if (t + 1 < NT2) {
            CVT_WRITE(nxt);                              // auto-wait retires B(t+1)
            if (t + 2 < NT2) {
                B_LOAD((t + 2) * BK2);
                asm volatile("s_waitcnt vmcnt(8)" ::: "memory");   // A(t+1) retired
            } else {
                asm volatile("s_waitcnt vmcnt(0)" ::: "memory");
            }
            asm volatile("s_waitcnt lgkmcnt(0)" ::: "memory");
            __builtin_amdgcn_sched_barrier(0);
            __builtin_amdgcn_s_barrier();                // nxt ready
        }
        cur = nxt;
    }
#undef A_DMA
#undef B_LOAD
#undef CVT_WRITE
#undef COMPUTE

    // C/D layout: col = lane&15, row = (lane>>4)*4 + reg.  Guarded stores.
    #pragma unroll
    for (int i = 0; i < 4; i++) {
        const int row = bm + wm * 64 + i * 16 + q * 4;
        #pragma unroll
        for (int j = 0; j < 4; j++) {
            const int col = bn + wn * 64 + j * 16 + r;
            #pragma unroll
            for (int reg = 0; reg < 4; reg++) {
                long idx = (long)(row + reg) * HV + col;
                if (idx < out_n) out[idx] = acc[i][j][reg];
            }
        }
    }
}

// ---------------- fallback GEMM: f32 inputs, register staging (proven) ----------------
__global__ __launch_bounds__(256) void gemm_f32in(
        const float* __restrict__ A, const float* __restrict__ B,
        float* __restrict__ out, long out_n) {
    __shared__ __align__(16) float lgA[BM * BKP];
    __shared__ __align__(16) float lgB[BN * BKP];

    const int tid  = threadIdx.x;
    const int lane = tid & 63;
    const int wave = tid >> 6;
    const int wm = wave & 1, wn = wave >> 1;
    const int q = lane >> 4, r = lane & 15;
    const int bm = blockIdx.y * BM;
    const int bn = blockIdx.x * BN;

    const int rg = lane >> 3;
    const int cg = (lane & 7) * 4;
    const float* gA = A + (size_t)(bm + wave * 32 + rg) * IN_DIM + cg;
    const float* gB = B + (size_t)(bn + wave * 32 + rg) * IN_DIM + cg;
    float* lA = &lgA[(wave * 32 + rg) * BKP + cg];
    float* lB = &lgB[(wave * 32 + rg) * BKP + cg];

    f32x4 acc[4][4] = {};

    for (int k0 = 0; k0 < IN_DIM; k0 += BK) {
        float4 va[4], vb[4];
        #pragma unroll
        for (int i = 0; i < 4; i++) {
            va[i] = *(const float4*)(gA + k0 + (size_t)(8 * i) * IN_DIM);
            vb[i] = *(const float4*)(gB + k0 + (size_t)(8 * i) * IN_DIM);
        }
        __syncthreads();
        #pragma unroll
        for (int i = 0; i < 4; i++) {
            *(float4*)(lA + 8 * i * BKP) = va[i];
            *(float4*)(lB + 8 * i * BKP) = vb[i];
        }
        __syncthreads();

        half8 af[4], bf[4];
        #pragma unroll
        for (int i = 0; i < 4; i++) {
            const float* p = &lgA[(wm * 64 + i * 16 + r) * BKP + q * 8];
            af[i] = pk8(*(const f32x4*)p, *(const f32x4*)(p + 4));
        }
        #pragma unroll
        for (int j = 0; j < 4; j++) {
            const float* p = &lgB[(wn * 64 + j * 16 + r) * BKP + q * 8];
            bf[j] = pk8(*(const f32x4*)p, *(const f32x4*)(p + 4));
        }

        #pragma unroll
        for (int i = 0; i < 4; i++)
            #pragma unroll
            for (int j = 0; j < 4; j++)
                acc[i][j] = __builtin_amdgcn_mfma_f32_16x16x32_f16(af[i], bf[j], acc[i][j], 0, 0, 0);
    }

    #pragma unroll
    for (int i = 0; i < 4; i++) {
        const int row = bm + wm * 64 + i * 16 + q * 4;
        #pragma unroll
        for (int j = 0; j < 4; j++) {
            const int col = bn + wn * 64 + j * 16 + r;
            #pragma unroll
            for (int reg = 0; reg < 4; reg++) {
                long idx = (long)(row + reg) * HV + col;
                if (idx < out_n) out[idx] = acc[i][j][reg];
            }
        }
    }
}

// ---------------- fused normalize + real-part 40-tap circular conv, in place ----------
// (R8-verified) 4 groups x 8 outputs/thread; float4 window, constant-folding WEL.
#define SW4(p4) ((p4) ^ (((p4) >> 3) & 7))
#define WEL(u) (((u) & 3) == 0 ? w4[(u) >> 2].x : ((u) & 3) == 1 ? w4[(u) >> 2].y : \
                ((u) & 3) == 2 ? w4[(u) >> 2].z : w4[(u) >> 2].w)
__global__ __launch_bounds__(256, 2) void norm_conv(float* __restrict__ out,
                                                    const float* __restrict__ qp,
                                                    const float* __restrict__ taps,
                                                    long out_n) {
    __shared__ __align__(16) float ldsv[40 + HV + 24];   // logical [p] = row[(p-40) mod HV]
    __shared__ float scr[NTAP];
    __shared__ float red[4];

    const int b = blockIdx.x;
    if ((long)(b + 1) * HV > out_n) return;

    const int tid = threadIdx.x;
    const int lane = tid & 63;
    const int wave = tid >> 6;
    float* rowp = out + (size_t)b * HV;
    const float4* row4 = (const float4*)rowp;
    float4* l4 = (float4*)ldsv;

    float ss = 0.f;
    #pragma unroll
    for (int it = 0; it < 8; it++) {
        int j = it * 256 + tid;
        float4 v = row4[j];
        ss += v.x * v.x + v.y * v.y + v.z * v.z + v.w * v.w;
        l4[SW4(10 + j)] = v;                    // logical float4 index 10+j, swizzled
    }
    if (tid < NTAP) {                           // circular halo: logical p = tid (0..39)
        ldsv[(SW4(tid >> 2) << 2) | (tid & 3)] = rowp[HV - NTAP + tid];
    }

    #pragma unroll
    for (int off = 32; off > 0; off >>= 1) ss += __shfl_down(ss, off, 64);
    if (lane == 0) red[wave] = ss;

    if (taps) {
        if (tid < NTAP) scr[tid] = taps[tid];   // precomputed by prep
    } else if (wave == 0) {
        float qv = (lane < 39) ? qp[lane] : 0.f;
        float pr = (lane == 0) ? 1.f : 0.f;
        float pim = 0.f;
        for (int t = 0; t < 39; t++) {
            float a = __shfl(qv, t, 64) * 0.5f;
            float c = cosf(a), s = sinf(a);
            float ur = __shfl_up(pr, 1, 64);
            float ui = __shfl_up(pim, 1, 64);
            if (lane == 0) { ur = 0.f; ui = 0.f; }
            float nr = c * pr - s * ui;
            float ni = c * pim + s * ur;
            pr = nr; pim = ni;
        }
        if (lane < NTAP) scr[lane] = pr;
    }
    __syncthreads();

    const float inv = 1.0f / sqrtf(red[0] + red[1] + red[2] + red[3]);
    float4* out4 = (float4*)rowp;

    #pragma unroll
    for (int g = 0; g < 4; g++) {
        float4 w4[12];
        #pragma unroll
        for (int t = 0; t < 12; t++) w4[t] = l4[SW4(8 * tid + 2 * g + t)];

        float av[8] = {};
        #pragma unroll
        for (int k = 0; k < NTAP; k++) {
            const float c = scr[k];             // LDS broadcast (free)
            #pragma unroll
            for (int o = 0; o < 8; o++) av[o] += c * WEL(40 + o - k);
        }
        const int f4 = 8 * tid + 2 * g;
        out4[f4]     = make_float4(inv * av[0], inv * av[1], inv * av[2], inv * av[3]);
        out4[f4 + 1] = make_float4(inv * av[4], inv * av[5], inv * av[6], inv * av[7]);
    }
}

// ---------------- launch ----------------
extern "C" void kernel_launch(void* const* d_in, const int* in_sizes, int n_in,
                              void* d_out, int out_size, void* d_ws, size_t ws_size,
                              hipStream_t stream) {
    const float* x  = (const float*)d_in[0];   // [1024][4096]
    const float* W  = (const float*)d_in[1];   // [8192][4096]
    const float* qp = (const float*)d_in[2];   // [39]
    float* out = (float*)d_out;                // [1024][8192] floats (Re of amps)
    long out_n = (long)out_size;

    const size_t need = (size_t)BATCH * IN_DIM * 2 + 256;  // xh (8 MB) + taps

    if (ws_size >= need) {
        _Float16* xh = (_Float16*)d_ws;
        float* taps = (float*)((char*)d_ws + (size_t)BATCH * IN_DIM * 2);
        int n4x = BATCH * IN_DIM / 4;          // 1,048,576 (= 4096 blocks of 256)
        prep<<<n4x / 256 + 1, 256, 0, stream>>>((const float4*)x, (half4v*)xh, n4x, qp, taps);
        dim3 grid2(HV / BN2, BATCH / BM2);     // (32, 8) = 256 blocks = 1/CU
        gemm_fused<<<grid2, 512, 0, stream>>>(xh, W, out, out_n);
        norm_conv<<<BATCH, 256, 0, stream>>>(out, qp, taps, out_n);
    } else {
        dim3 grid(HV / BN, BATCH / BM);        // (64, 8)
        gemm_f32in<<<grid, 256, 0, stream>>>(x, W, out, out_n);
        norm_conv<<<BATCH, 256, 0, stream>>>(out, qp, nullptr, out_n);
    }
}

// Round 10
// 313.715 us; speedup vs baseline: 1.0148x; 1.0148x over previous
//
#include <hip/hip_runtime.h>
#include <hip/hip_fp16.h>
#include <math.h>

typedef _Float16 half8 __attribute__((ext_vector_type(8)));
typedef __fp16 fp16x2 __attribute__((ext_vector_type(2)));
typedef float f32x4 __attribute__((ext_vector_type(4)));

#define BATCH 1024
#define IN_DIM 4096
#define HV 8192
#define NTAP 40          // 39 gates -> degree-39 polynomial -> 40 taps

#define BM 128
#define BN 128
#define BKP 36           // f32 fallback LDS row stride

// gemm geometry: 128x128 tile, BK=32, 3 LDS buffers, 2 blocks/CU
#define BK3 32
#define NT3 (IN_DIM / BK3)       // 128 K-tiles
#define ASZ3 (BM * BK3)          // 4096 f16 (8 KB)
#define TSZ3 (2 * ASZ3)          // 8192 f16 (16 KB) per buffer (A+B)

#define GLD16(g, l) __builtin_amdgcn_global_load_lds(                          \
    (const __attribute__((address_space(1))) void*)(g),                        \
    (__attribute__((address_space(3))) void*)(l), 16, 0, 0)

// pack 8 f32 -> 8 f16 (RTZ), 4 VALU instrs (fallback path only)
static __device__ __forceinline__ half8 pk8(f32x4 a, f32x4 b) {
    union { fp16x2 p[4]; half8 h; } u;
    u.p[0] = __builtin_amdgcn_cvt_pkrtz(a.x, a.y);
    u.p[1] = __builtin_amdgcn_cvt_pkrtz(a.z, a.w);
    u.p[2] = __builtin_amdgcn_cvt_pkrtz(b.x, b.y);
    u.p[3] = __builtin_amdgcn_cvt_pkrtz(b.z, b.w);
    return u.h;
}

typedef _Float16 half4v __attribute__((ext_vector_type(4)));

// ---------------- prep: cvt x + cvt W (f32->f16, RNE) + taps, ONE launch ----------
__global__ __launch_bounds__(256) void prep(const float4* __restrict__ xsrc, int n4x,
                                            const float4* __restrict__ wsrc, int n4w,
                                            half4v* __restrict__ xdst,
                                            half4v* __restrict__ wdst,
                                            const float* __restrict__ qp,
                                            float* __restrict__ taps) {
    long i = (long)blockIdx.x * 256 + threadIdx.x;
    if (i < n4x) {
        float4 v = xsrc[i];
        half4v h;
        h.x = (_Float16)v.x; h.y = (_Float16)v.y;
        h.z = (_Float16)v.z; h.w = (_Float16)v.w;
        xdst[i] = h;
    } else if (i < (long)n4x + n4w) {
        long j = i - n4x;
        float4 v = wsrc[j];
        half4v h;
        h.x = (_Float16)v.x; h.y = (_Float16)v.y;
        h.z = (_Float16)v.z; h.w = (_Float16)v.w;
        wdst[j] = h;
    } else if (threadIdx.x < 64) {
        // single extra block: gate-polynomial taps (1 wave)
        const int lane = threadIdx.x;
        float qv = (lane < 39) ? qp[lane] : 0.f;
        float pr = (lane == 0) ? 1.f : 0.f;
        float pim = 0.f;
        for (int t = 0; t < 39; t++) {
            float a = __shfl(qv, t, 64) * 0.5f;
            float c = cosf(a), s = sinf(a);
            float ur = __shfl_up(pr, 1, 64);
            float ui = __shfl_up(pim, 1, 64);
            if (lane == 0) { ur = 0.f; ui = 0.f; }
            float nr = c * pr - s * ui;
            float ni = c * pim + s * ur;
            pr = nr; pim = ni;
        }
        if (lane < NTAP) taps[lane] = pr;
    }
}

// ---------------- primary GEMM: R5 counted-vmcnt 3-buffer schedule @ 128x128/BK32 ----
// 256 threads = 4 waves (2M x 2N), 64x64 per wave.  Grid 64x8 = 512 = 2 blocks/CU.
// LDS 3 x 16 KB = 48 KB -> TWO blocks resident: when one block sits in its vmcnt
// gate/barrier, the other computes (cross-block overlap R5's 144 KB config lacked).
// Schedule identical to R5 (verified): vmcnt(4) -> barrier -> STAGE(t+2) -> COMPUTE(t);
// 2 K-tiles of loads always in flight; vmcnt never drains to 0 until the last tile.
// LDS swizzle = R1's verified-zero-conflict BK=32 form: physical 16B slot s of row R
// holds source chunk s ^ ((R>>1)&3); GLD16 dest linear, global source inverse-swizzled.
__global__ __launch_bounds__(256, 2) void gemm_f16(
        const _Float16* __restrict__ A,   // [BATCH][IN_DIM] f16
        const _Float16* __restrict__ B,   // [HV][IN_DIM]   f16
        float* __restrict__ out,          // classical [BATCH][HV]
        long out_n) {
    __shared__ __align__(16) _Float16 lds[3 * TSZ3];   // 48 KB

    const int tid  = threadIdx.x;
    const int lane = tid & 63;
    const int wave = tid >> 6;          // 0..3
    const int wm = wave & 1;            // 2 waves in M (64 rows each)
    const int wn = wave >> 1;           // 2 waves in N (64 cols each)
    const int q = lane >> 4, r = lane & 15;
    const int bm = blockIdx.y * BM;
    const int bn = blockIdx.x * BN;

    // ---- staging: tile = 128 rows x 4 slots = 512 chunks of 16B; thread covers
    // p = h*256+tid (h=0,1) for A and for B.  chunk p: row R=p>>2, physical slot
    // s=p&3 holds source chunk c = s ^ ((R>>1)&3).
    const _Float16* srcA[2];
    const _Float16* srcB[2];
    int dAB[2];
    #pragma unroll
    for (int h = 0; h < 2; h++) {
        const int p = h * 256 + tid;
        const int R = p >> 2, c = (p & 3) ^ ((R >> 1) & 3);
        srcA[h] = A + (size_t)(bm + R) * IN_DIM + c * 8;
        srcB[h] = B + (size_t)(bn + R) * IN_DIM + c * 8;
        dAB[h] = (h * 256 + wave * 64) * 8;          // wave-uniform; HW adds lane*16B
    }

    f32x4 acc[4][4] = {};

#define STAGE(u, k0)  do {                                   \
        _Float16* bp = &lds[(u) * TSZ3];                     \
        GLD16(srcA[0] + (k0), bp + dAB[0]);                  \
        GLD16(srcA[1] + (k0), bp + dAB[1]);                  \
        GLD16(srcB[0] + (k0), bp + ASZ3 + dAB[0]);           \
        GLD16(srcB[1] + (k0), bp + ASZ3 + dAB[1]);           \
    } while (0)

    // fragment reads: row R (stride 32 f16), logical slot q, physical q^((R>>1)&3).
    // R = w*64 + i*16 + r  ->  (R>>1)&3 = ((r>>1)&3) since 64,16 contribute 0 mod 8.
#define COMPUTE(u)  do {                                                            \
        const _Float16* bp = &lds[(u) * TSZ3];                                      \
        half8 af[4], bf[4];                                                         \
        const int sw = (q ^ ((r >> 1) & 3)) * 8;                                    \
        _Pragma("unroll")                                                           \
        for (int i = 0; i < 4; i++) {                                               \
            const int R = wm * 64 + i * 16 + r;                                     \
            af[i] = *(const half8*)&bp[R * 32 + sw];                                \
        }                                                                           \
        _Pragma("unroll")                                                           \
        for (int j = 0; j < 4; j++) {                                               \
            const int R = wn * 64 + j * 16 + r;                                     \
            bf[j] = *(const half8*)&bp[ASZ3 + R * 32 + sw];                         \
        }                                                                           \
        __builtin_amdgcn_s_setprio(1);                                              \
        _Pragma("unroll")                                                           \
        for (int i = 0; i < 4; i++)                                                 \
            _Pragma("unroll")                                                       \
            for (int j = 0; j < 4; j++)                                             \
                acc[i][j] = __builtin_amdgcn_mfma_f32_16x16x32_f16(                 \
                    af[i], bf[j], acc[i][j], 0, 0, 0);                              \
        __builtin_amdgcn_s_setprio(0);                                              \
    } while (0)

    STAGE(0, 0);
    STAGE(1, BK3);
    int cur = 0;
    for (int t = 0; t < NT3 - 1; ++t) {
        asm volatile("s_waitcnt vmcnt(4)" ::: "memory");   // tile t landed; t+1 in flight
        __builtin_amdgcn_sched_barrier(0);
        __builtin_amdgcn_s_barrier();
        if (t + 2 < NT3) {
            const int nxt = (cur + 2 >= 3) ? cur - 1 : cur + 2;
            STAGE(nxt, (t + 2) * BK3);
        }
        COMPUTE(cur);
        cur = (cur + 1 == 3) ? 0 : cur + 1;
    }
    asm volatile("s_waitcnt vmcnt(0)" ::: "memory");       // final tile fully staged
    __builtin_amdgcn_sched_barrier(0);
    __builtin_amdgcn_s_barrier();
    COMPUTE(cur);
#undef STAGE
#undef COMPUTE

    // C/D layout: col = lane&15, row = (lane>>4)*4 + reg.  Guarded stores.
    #pragma unroll
    for (int i = 0; i < 4; i++) {
        const int row = bm + wm * 64 + i * 16 + q * 4;
        #pragma unroll
        for (int j = 0; j < 4; j++) {
            const int col = bn + wn * 64 + j * 16 + r;
            #pragma unroll
            for (int reg = 0; reg < 4; reg++) {
                long idx = (long)(row + reg) * HV + col;
                if (idx < out_n) out[idx] = acc[i][j][reg];
            }
        }
    }
}

// ---------------- fallback GEMM: f32 inputs, register staging (proven) ----------------
__global__ __launch_bounds__(256) void gemm_f32in(
        const float* __restrict__ A, const float* __restrict__ B,
        float* __restrict__ out, long out_n) {
    __shared__ __align__(16) float lgA[BM * BKP];
    __shared__ __align__(16) float lgB[BN * BKP];

    const int tid  = threadIdx.x;
    const int lane = tid & 63;
    const int wave = tid >> 6;
    const int wm = wave & 1, wn = wave >> 1;
    const int q = lane >> 4, r = lane & 15;
    const int bm = blockIdx.y * BM;
    const int bn = blockIdx.x * BN;

    const int rg = lane >> 3;
    const int cg = (lane & 7) * 4;
    const float* gA = A + (size_t)(bm + wave * 32 + rg) * IN_DIM + cg;
    const float* gB = B + (size_t)(bn + wave * 32 + rg) * IN_DIM + cg;
    float* lA = &lgA[(wave * 32 + rg) * BKP + cg];
    float* lB = &lgB[(wave * 32 + rg) * BKP + cg];

    f32x4 acc[4][4] = {};

    for (int k0 = 0; k0 < IN_DIM; k0 += 32) {
        float4 va[4], vb[4];
        #pragma unroll
        for (int i = 0; i < 4; i++) {
            va[i] = *(const float4*)(gA + k0 + (size_t)(8 * i) * IN_DIM);
            vb[i] = *(const float4*)(gB + k0 + (size_t)(8 * i) * IN_DIM);
        }
        __syncthreads();
        #pragma unroll
        for (int i = 0; i < 4; i++) {
            *(float4*)(lA + 8 * i * BKP) = va[i];
            *(float4*)(lB + 8 * i * BKP) = vb[i];
        }
        __syncthreads();

        half8 af[4], bf[4];
        #pragma unroll
        for (int i = 0; i < 4; i++) {
            const float* p = &lgA[(wm * 64 + i * 16 + r) * BKP + q * 8];
            af[i] = pk8(*(const f32x4*)p, *(const f32x4*)(p + 4));
        }
        #pragma unroll
        for (int j = 0; j < 4; j++) {
            const float* p = &lgB[(wn * 64 + j * 16 + r) * BKP + q * 8];
            bf[j] = pk8(*(const f32x4*)p, *(const f32x4*)(p + 4));
        }

        #pragma unroll
        for (int i = 0; i < 4; i++)
            #pragma unroll
            for (int j = 0; j < 4; j++)
                acc[i][j] = __builtin_amdgcn_mfma_f32_16x16x32_f16(af[i], bf[j], acc[i][j], 0, 0, 0);
    }

    #pragma unroll
    for (int i = 0; i < 4; i++) {
        const int row = bm + wm * 64 + i * 16 + q * 4;
        #pragma unroll
        for (int j = 0; j < 4; j++) {
            const int col = bn + wn * 64 + j * 16 + r;
            #pragma unroll
            for (int reg = 0; reg < 4; reg++) {
                long idx = (long)(row + reg) * HV + col;
                if (idx < out_n) out[idx] = acc[i][j][reg];
            }
        }
    }
}

// ---------------- fused normalize + real-part 40-tap circular conv, in place ----------
// (R8-verified) 4 groups x 8 outputs/thread; float4 window, constant-folding WEL.
#define SW4(p4) ((p4) ^ (((p4) >> 3) & 7))
#define WEL(u) (((u) & 3) == 0 ? w4[(u) >> 2].x : ((u) & 3) == 1 ? w4[(u) >> 2].y : \
                ((u) & 3) == 2 ? w4[(u) >> 2].z : w4[(u) >> 2].w)
__global__ __launch_bounds__(256, 2) void norm_conv(float* __restrict__ out,
                                                    const float* __restrict__ qp,
                                                    const float* __restrict__ taps,
                                                    long out_n) {
    __shared__ __align__(16) float ldsv[40 + HV + 24];   // logical [p] = row[(p-40) mod HV]
    __shared__ float scr[NTAP];
    __shared__ float red[4];

    const int b = blockIdx.x;
    if ((long)(b + 1) * HV > out_n) return;

    const int tid = threadIdx.x;
    const int lane = tid & 63;
    const int wave = tid >> 6;
    float* rowp = out + (size_t)b * HV;
    const float4* row4 = (const float4*)rowp;
    float4* l4 = (float4*)ldsv;

    float ss = 0.f;
    #pragma unroll
    for (int it = 0; it < 8; it++) {
        int j = it * 256 + tid;
        float4 v = row4[j];
        ss += v.x * v.x + v.y * v.y + v.z * v.z + v.w * v.w;
        l4[SW4(10 + j)] = v;                    // logical float4 index 10+j, swizzled
    }
    if (tid < NTAP) {                           // circular halo: logical p = tid (0..39)
        ldsv[(SW4(tid >> 2) << 2) | (tid & 3)] = rowp[HV - NTAP + tid];
    }

    #pragma unroll
    for (int off = 32; off > 0; off >>= 1) ss += __shfl_down(ss, off, 64);
    if (lane == 0) red[wave] = ss;

    if (taps) {
        if (tid < NTAP) scr[tid] = taps[tid];   // precomputed by prep
    } else if (wave == 0) {
        float qv = (lane < 39) ? qp[lane] : 0.f;
        float pr = (lane == 0) ? 1.f : 0.f;
        float pim = 0.f;
        for (int t = 0; t < 39; t++) {
            float a = __shfl(qv, t, 64) * 0.5f;
            float c = cosf(a), s = sinf(a);
            float ur = __shfl_up(pr, 1, 64);
            float ui = __shfl_up(pim, 1, 64);
            if (lane == 0) { ur = 0.f; ui = 0.f; }
            float nr = c * pr - s * ui;
            float ni = c * pim + s * ur;
            pr = nr; pim = ni;
        }
        if (lane < NTAP) scr[lane] = pr;
    }
    __syncthreads();

    const float inv = 1.0f / sqrtf(red[0] + red[1] + red[2] + red[3]);
    float4* out4 = (float4*)rowp;

    #pragma unroll
    for (int g = 0; g < 4; g++) {
        float4 w4[12];
        #pragma unroll
        for (int t = 0; t < 12; t++) w4[t] = l4[SW4(8 * tid + 2 * g + t)];

        float av[8] = {};
        #pragma unroll
        for (int k = 0; k < NTAP; k++) {
            const float c = scr[k];             // LDS broadcast (free)
            #pragma unroll
            for (int o = 0; o < 8; o++) av[o] += c * WEL(40 + o - k);
        }
        const int f4 = 8 * tid + 2 * g;
        out4[f4]     = make_float4(inv * av[0], inv * av[1], inv * av[2], inv * av[3]);
        out4[f4 + 1] = make_float4(inv * av[4], inv * av[5], inv * av[6], inv * av[7]);
    }
}

// ---------------- launch ----------------
extern "C" void kernel_launch(void* const* d_in, const int* in_sizes, int n_in,
                              void* d_out, int out_size, void* d_ws, size_t ws_size,
                              hipStream_t stream) {
    const float* x  = (const float*)d_in[0];   // [1024][4096]
    const float* W  = (const float*)d_in[1];   // [8192][4096]
    const float* qp = (const float*)d_in[2];   // [39]
    float* out = (float*)d_out;                // [1024][8192] floats (Re of amps)
    long out_n = (long)out_size;

    const size_t need = (size_t)BATCH * IN_DIM * 2 + (size_t)HV * IN_DIM * 2 + 256;

    if (ws_size >= need) {
        _Float16* xh = (_Float16*)d_ws;
        _Float16* wh = xh + (size_t)BATCH * IN_DIM;
        float* taps = (float*)((char*)d_ws + need - 256);
        const int n4x = BATCH * IN_DIM / 4;    // 1,048,576
        const int n4w = HV * IN_DIM / 4;       // 8,388,608
        const int nblk = (n4x + n4w) / 256 + 1;  // exact cover + 1 taps block
        prep<<<nblk, 256, 0, stream>>>((const float4*)x, n4x, (const float4*)W, n4w,
                                       (half4v*)xh, (half4v*)wh, qp, taps);
        dim3 grid(HV / BN, BATCH / BM);        // (64, 8) = 512 blocks = 2/CU
        gemm_f16<<<grid, 256, 0, stream>>>(xh, wh, out, out_n);
        norm_conv<<<BATCH, 256, 0, stream>>>(out, qp, taps, out_n);
    } else {
        dim3 grid(HV / BN, BATCH / BM);        // (64, 8)
        gemm_f32in<<<grid, 256, 0, stream>>>(x, W, out, out_n);
        norm_conv<<<BATCH, 256, 0, stream>>>(out, qp, nullptr, out_n);
    }
}

// Round 13
// 303.127 us; speedup vs baseline: 1.0502x; 1.0349x over previous
//
#include <hip/hip_runtime.h>
#include <hip/hip_fp16.h>
#include <math.h>

typedef _Float16 half8 __attribute__((ext_vector_type(8)));
typedef __fp16 fp16x2 __attribute__((ext_vector_type(2)));
typedef float f32x4 __attribute__((ext_vector_type(4)));

#define BATCH 1024
#define IN_DIM 4096
#define HV 8192
#define NTAP 40          // 39 gates -> degree-39 polynomial -> 40 taps

#define BM 128
#define BN 128
#define BKP 36           // f32 fallback LDS row stride

// champion gemm geometry (R5-verified: 82.7 us, MfmaUtil 35.5%, conflicts 0)
#define BM2 128
#define BN2 256
#define BK2 64
#define NT2 (IN_DIM / BK2)       // 64 K-tiles
#define ASZ (BM2 * BK2)          // 8192 f16 (16 KB)
#define BSZ (BN2 * BK2)          // 16384 f16 (32 KB)
#define TSZ (ASZ + BSZ)          // 24576 f16 (48 KB) per buffer

#define GLD16(g, l) __builtin_amdgcn_global_load_lds(                          \
    (const __attribute__((address_space(1))) void*)(g),                        \
    (__attribute__((address_space(3))) void*)(l), 16, 0, 0)

// pack 8 f32 -> 8 f16 (RTZ), 4 VALU instrs (fallback path only)
static __device__ __forceinline__ half8 pk8(f32x4 a, f32x4 b) {
    union { fp16x2 p[4]; half8 h; } u;
    u.p[0] = __builtin_amdgcn_cvt_pkrtz(a.x, a.y);
    u.p[1] = __builtin_amdgcn_cvt_pkrtz(a.z, a.w);
    u.p[2] = __builtin_amdgcn_cvt_pkrtz(b.x, b.y);
    u.p[3] = __builtin_amdgcn_cvt_pkrtz(b.z, b.w);
    return u.h;
}

typedef _Float16 half4v __attribute__((ext_vector_type(4)));

// ---------------- prep: cvt x + cvt W (f32->f16, RNE) + taps, ONE launch ----------
__global__ __launch_bounds__(256) void prep(const float4* __restrict__ xsrc, int n4x,
                                            const float4* __restrict__ wsrc, int n4w,
                                            half4v* __restrict__ xdst,
                                            half4v* __restrict__ wdst,
                                            const float* __restrict__ qp,
                                            float* __restrict__ taps) {
    long i = (long)blockIdx.x * 256 + threadIdx.x;
    if (i < n4x) {
        float4 v = xsrc[i];
        half4v h;
        h.x = (_Float16)v.x; h.y = (_Float16)v.y;
        h.z = (_Float16)v.z; h.w = (_Float16)v.w;
        xdst[i] = h;
    } else if (i < (long)n4x + n4w) {
        long j = i - n4x;
        float4 v = wsrc[j];
        half4v h;
        h.x = (_Float16)v.x; h.y = (_Float16)v.y;
        h.z = (_Float16)v.z; h.w = (_Float16)v.w;
        wdst[j] = h;
    } else if (threadIdx.x < 64) {
        // single extra block: gate-polynomial taps (1 wave)
        const int lane = threadIdx.x;
        float qv = (lane < 39) ? qp[lane] : 0.f;
        float pr = (lane == 0) ? 1.f : 0.f;
        float pim = 0.f;
        for (int t = 0; t < 39; t++) {
            float a = __shfl(qv, t, 64) * 0.5f;
            float c = cosf(a), s = sinf(a);
            float ur = __shfl_up(pr, 1, 64);
            float ui = __shfl_up(pim, 1, 64);
            if (lane == 0) { ur = 0.f; ui = 0.f; }
            float nr = c * pr - s * ui;
            float ni = c * pim + s * ur;
            pr = nr; pim = ni;
        }
        if (lane < NTAP) taps[lane] = pr;
    }
}

// ---------------- primary GEMM: counted-vmcnt triple-buffer pipeline (R5, champion) ----
// 128(M) x 256(N) tile, BK=64, 512 threads = 8 waves (2M x 4N), 64x64 per wave.
// Grid 32x8 = 256 blocks = 1/CU.  LDS 3 x 48 KB; 2 K-tiles of loads in flight.
// s_waitcnt vmcnt(6) -> barrier -> STAGE(t+2) -> ds_read+MFMA(t).  Measured 82.7 us
// (R5) / 83.0 (R8); session-best.  Session evidence that this is the floor for this
// shape: 2-barrier 93.6, 4-phase 86, fixed 4-phase 86.5, 128^2 2-blocks/CU 86.0 --
// all within 4 us of the same LDS-read-instruction-bound plateau; m201's 256^2
// escape needs >=256-block grids, impossible at M=1024.
__global__ __launch_bounds__(512, 2) void gemm_f16(
        const _Float16* __restrict__ A,   // [BATCH][IN_DIM] f16
        const _Float16* __restrict__ B,   // [HV][IN_DIM]   f16
        float* __restrict__ out,          // classical [BATCH][HV]
        long out_n) {
    __shared__ __align__(16) _Float16 lds[3 * TSZ];   // 144 KB

    const int tid  = threadIdx.x;
    const int lane = tid & 63;
    const int wave = tid >> 6;          // 0..7
    const int wm = wave & 1;            // 2 waves in M (64 rows each)
    const int wn = wave >> 1;           // 4 waves in N (64 cols each)
    const int q = lane >> 4, r = lane & 15;
    const int bm = blockIdx.y * BM2;
    const int bn = blockIdx.x * BN2;

    // ---- staging addresses (fixed per thread; += k0 per tile) ----
    // slot p -> row R=p>>3, physical slot s=p&7 holds source chunk c = s ^ (R&7)
    const _Float16* srcA[2];
    int dA[2];
    #pragma unroll
    for (int h = 0; h < 2; h++) {
        const int p = h * 512 + tid;
        const int R = p >> 3, c = (p & 7) ^ (R & 7);
        srcA[h] = A + (size_t)(bm + R) * IN_DIM + c * 8;
        dA[h] = (h * 512 + wave * 64) * 8;           // wave-uniform; HW adds lane*16B
    }
    const _Float16* srcB[4];
    int dB[4];
    #pragma unroll
    for (int h = 0; h < 4; h++) {
        const int p = h * 512 + tid;
        const int R = p >> 3, c = (p & 7) ^ (R & 7);
        srcB[h] = B + (size_t)(bn + R) * IN_DIM + c * 8;
        dB[h] = ASZ + (h * 512 + wave * 64) * 8;
    }

    f32x4 acc[4][4] = {};

#define STAGE(u, k0)  do {                                   \
        _Float16* bp = &lds[(u) * TSZ];                      \
        GLD16(srcA[0] + (k0), bp + dA[0]);                   \
        GLD16(srcA[1] + (k0), bp + dA[1]);                   \
        GLD16(srcB[0] + (k0), bp + dB[0]);                   \
        GLD16(srcB[1] + (k0), bp + dB[1]);                   \
        GLD16(srcB[2] + (k0), bp + dB[2]);                   \
        GLD16(srcB[3] + (k0), bp + dB[3]);                   \
    } while (0)

    // fragment LDS offsets: row R (stride 64 f16), logical slot s=kk*4+q,
    // physical slot s^(R&7) = s^(r&7) since 64|wm*64 and 16|i*16.
#define COMPUTE(u)  do {                                                            \
        const _Float16* bp = &lds[(u) * TSZ];                                       \
        half8 af[4][2], bf[4][2];                                                   \
        _Pragma("unroll")                                                           \
        for (int i = 0; i < 4; i++)                                                 \
            _Pragma("unroll")                                                       \
            for (int kk = 0; kk < 2; kk++) {                                        \
                const int R = wm * 64 + i * 16 + r;                                 \
                const int sw = (kk * 4 + q) ^ (r & 7);                              \
                af[i][kk] = *(const half8*)&bp[R * 64 + sw * 8];                    \
            }                                                                       \
        _Pragma("unroll")                                                           \
        for (int j = 0; j < 4; j++)                                                 \
            _Pragma("unroll")                                                       \
            for (int kk = 0; kk < 2; kk++) {                                        \
                const int R = wn * 64 + j * 16 + r;                                 \
                const int sw = (kk * 4 + q) ^ (r & 7);                              \
                bf[j][kk] = *(const half8*)&bp[ASZ + R * 64 + sw * 8];              \
            }                                                                       \
        __builtin_amdgcn_s_setprio(1);                                              \
        _Pragma("unroll")                                                           \
        for (int i = 0; i < 4; i++)                                                 \
            _Pragma("unroll")                                                       \
            for (int j = 0; j < 4; j++)                                             \
                _Pragma("unroll")                                                   \
                for (int kk = 0; kk < 2; kk++)                                      \
                    acc[i][j] = __builtin_amdgcn_mfma_f32_16x16x32_f16(             \
                        af[i][kk], bf[j][kk], acc[i][j], 0, 0, 0);                  \
        __builtin_amdgcn_s_setprio(0);                                              \
    } while (0)

    STAGE(0, 0);
    STAGE(1, BK2);
    int cur = 0;
    for (int t = 0; t < NT2 - 1; ++t) {
        asm volatile("s_waitcnt vmcnt(6)" ::: "memory");   // tile t landed; t+1 in flight
        __builtin_amdgcn_sched_barrier(0);
        __builtin_amdgcn_s_barrier();
        if (t + 2 < NT2) {
            const int nxt = (cur + 2 >= 3) ? cur - 1 : cur + 2;
            STAGE(nxt, (t + 2) * BK2);
        }
        COMPUTE(cur);
        cur = (cur + 1 == 3) ? 0 : cur + 1;
    }
    asm volatile("s_waitcnt vmcnt(0)" ::: "memory");       // final tile fully staged
    __builtin_amdgcn_sched_barrier(0);
    __builtin_amdgcn_s_barrier();
    COMPUTE(cur);
#undef STAGE
#undef COMPUTE

    // C/D layout: col = lane&15, row = (lane>>4)*4 + reg.  Guarded stores.
    #pragma unroll
    for (int i = 0; i < 4; i++) {
        const int row = bm + wm * 64 + i * 16 + q * 4;
        #pragma unroll
        for (int j = 0; j < 4; j++) {
            const int col = bn + wn * 64 + j * 16 + r;
            #pragma unroll
            for (int reg = 0; reg < 4; reg++) {
                long idx = (long)(row + reg) * HV + col;
                if (idx < out_n) out[idx] = acc[i][j][reg];
            }
        }
    }
}

// ---------------- fallback GEMM: f32 inputs, register staging (proven) ----------------
__global__ __launch_bounds__(256) void gemm_f32in(
        const float* __restrict__ A, const float* __restrict__ B,
        float* __restrict__ out, long out_n) {
    __shared__ __align__(16) float lgA[BM * BKP];
    __shared__ __align__(16) float lgB[BN * BKP];

    const int tid  = threadIdx.x;
    const int lane = tid & 63;
    const int wave = tid >> 6;
    const int wm = wave & 1, wn = wave >> 1;
    const int q = lane >> 4, r = lane & 15;
    const int bm = blockIdx.y * BM;
    const int bn = blockIdx.x * BN;

    const int rg = lane >> 3;
    const int cg = (lane & 7) * 4;
    const float* gA = A + (size_t)(bm + wave * 32 + rg) * IN_DIM + cg;
    const float* gB = B + (size_t)(bn + wave * 32 + rg) * IN_DIM + cg;
    float* lA = &lgA[(wave * 32 + rg) * BKP + cg];
    float* lB = &lgB[(wave * 32 + rg) * BKP + cg];

    f32x4 acc[4][4] = {};

    for (int k0 = 0; k0 < IN_DIM; k0 += 32) {
        float4 va[4], vb[4];
        #pragma unroll
        for (int i = 0; i < 4; i++) {
            va[i] = *(const float4*)(gA + k0 + (size_t)(8 * i) * IN_DIM);
            vb[i] = *(const float4*)(gB + k0 + (size_t)(8 * i) * IN_DIM);
        }
        __syncthreads();
        #pragma unroll
        for (int i = 0; i < 4; i++) {
            *(float4*)(lA + 8 * i * BKP) = va[i];
            *(float4*)(lB + 8 * i * BKP) = vb[i];
        }
        __syncthreads();

        half8 af[4], bf[4];
        #pragma unroll
        for (int i = 0; i < 4; i++) {
            const float* p = &lgA[(wm * 64 + i * 16 + r) * BKP + q * 8];
            af[i] = pk8(*(const f32x4*)p, *(const f32x4*)(p + 4));
        }
        #pragma unroll
        for (int j = 0; j < 4; j++) {
            const float* p = &lgB[(wn * 64 + j * 16 + r) * BKP + q * 8];
            bf[j] = pk8(*(const f32x4*)p, *(const f32x4*)(p + 4));
        }

        #pragma unroll
        for (int i = 0; i < 4; i++)
            #pragma unroll
            for (int j = 0; j < 4; j++)
                acc[i][j] = __builtin_amdgcn_mfma_f32_16x16x32_f16(af[i], bf[j], acc[i][j], 0, 0, 0);
    }

    #pragma unroll
    for (int i = 0; i < 4; i++) {
        const int row = bm + wm * 64 + i * 16 + q * 4;
        #pragma unroll
        for (int j = 0; j < 4; j++) {
            const int col = bn + wn * 64 + j * 16 + r;
            #pragma unroll
            for (int reg = 0; reg < 4; reg++) {
                long idx = (long)(row + reg) * HV + col;
                if (idx < out_n) out[idx] = acc[i][j][reg];
            }
        }
    }
}

// ---------------- fused normalize + real-part 40-tap circular conv, in place ----------
// (R8-verified) 4 groups x 8 outputs/thread; float4 window, constant-folding WEL.
#define SW4(p4) ((p4) ^ (((p4) >> 3) & 7))
#define WEL(u) (((u) & 3) == 0 ? w4[(u) >> 2].x : ((u) & 3) == 1 ? w4[(u) >> 2].y : \
                ((u) & 3) == 2 ? w4[(u) >> 2].z : w4[(u) >> 2].w)
__global__ __launch_bounds__(256, 2) void norm_conv(float* __restrict__ out,
                                                    const float* __restrict__ qp,
                                                    const float* __restrict__ taps,
                                                    long out_n) {
    __shared__ __align__(16) float ldsv[40 + HV + 24];   // logical [p] = row[(p-40) mod HV]
    __shared__ float scr[NTAP];
    __shared__ float red[4];

    const int b = blockIdx.x;
    if ((long)(b + 1) * HV > out_n) return;

    const int tid = threadIdx.x;
    const int lane = tid & 63;
    const int wave = tid >> 6;
    float* rowp = out + (size_t)b * HV;
    const float4* row4 = (const float4*)rowp;
    float4* l4 = (float4*)ldsv;

    float ss = 0.f;
    #pragma unroll
    for (int it = 0; it < 8; it++) {
        int j = it * 256 + tid;
        float4 v = row4[j];
        ss += v.x * v.x + v.y * v.y + v.z * v.z + v.w * v.w;
        l4[SW4(10 + j)] = v;                    // logical float4 index 10+j, swizzled
    }
    if (tid < NTAP) {                           // circular halo: logical p = tid (0..39)
        ldsv[(SW4(tid >> 2) << 2) | (tid & 3)] = rowp[HV - NTAP + tid];
    }

    #pragma unroll
    for (int off = 32; off > 0; off >>= 1) ss += __shfl_down(ss, off, 64);
    if (lane == 0) red[wave] = ss;

    if (taps) {
        if (tid < NTAP) scr[tid] = taps[tid];   // precomputed by prep
    } else if (wave == 0) {
        float qv = (lane < 39) ? qp[lane] : 0.f;
        float pr = (lane == 0) ? 1.f : 0.f;
        float pim = 0.f;
        for (int t = 0; t < 39; t++) {
            float a = __shfl(qv, t, 64) * 0.5f;
            float c = cosf(a), s = sinf(a);
            float ur = __shfl_up(pr, 1, 64);
            float ui = __shfl_up(pim, 1, 64);
            if (lane == 0) { ur = 0.f; ui = 0.f; }
            float nr = c * pr - s * ui;
            float ni = c * pim + s * ur;
            pr = nr; pim = ni;
        }
        if (lane < NTAP) scr[lane] = pr;
    }
    __syncthreads();

    const float inv = 1.0f / sqrtf(red[0] + red[1] + red[2] + red[3]);
    float4* out4 = (float4*)rowp;

    #pragma unroll
    for (int g = 0; g < 4; g++) {
        float4 w4[12];
        #pragma unroll
        for (int t = 0; t < 12; t++) w4[t] = l4[SW4(8 * tid + 2 * g + t)];

        float av[8] = {};
        #pragma unroll
        for (int k = 0; k < NTAP; k++) {
            const float c = scr[k];             // LDS broadcast (free)
            #pragma unroll
            for (int o = 0; o < 8; o++) av[o] += c * WEL(40 + o - k);
        }
        const int f4 = 8 * tid + 2 * g;
        out4[f4]     = make_float4(inv * av[0], inv * av[1], inv * av[2], inv * av[3]);
        out4[f4 + 1] = make_float4(inv * av[4], inv * av[5], inv * av[6], inv * av[7]);
    }
}

// ---------------- launch ----------------
extern "C" void kernel_launch(void* const* d_in, const int* in_sizes, int n_in,
                              void* d_out, int out_size, void* d_ws, size_t ws_size,
                              hipStream_t stream) {
    const float* x  = (const float*)d_in[0];   // [1024][4096]
    const float* W  = (const float*)d_in[1];   // [8192][4096]
    const float* qp = (const float*)d_in[2];   // [39]
    float* out = (float*)d_out;                // [1024][8192] floats (Re of amps)
    long out_n = (long)out_size;

    const size_t need = (size_t)BATCH * IN_DIM * 2 + (size_t)HV * IN_DIM * 2 + 256;

    if (ws_size >= need) {
        _Float16* xh = (_Float16*)d_ws;
        _Float16* wh = xh + (size_t)BATCH * IN_DIM;
        float* taps = (float*)((char*)d_ws + need - 256);
        const int n4x = BATCH * IN_DIM / 4;    // 1,048,576
        const int n4w = HV * IN_DIM / 4;       // 8,388,608
        const int nblk = (n4x + n4w) / 256 + 1;  // exact cover + 1 taps block
        prep<<<nblk, 256, 0, stream>>>((const float4*)x, n4x, (const float4*)W, n4w,
                                       (half4v*)xh, (half4v*)wh, qp, taps);
        dim3 grid2(HV / BN2, BATCH / BM2);     // (32, 8) = 256 blocks = 1/CU
        gemm_f16<<<grid2, 512, 0, stream>>>(xh, wh, out, out_n);
        norm_conv<<<BATCH, 256, 0, stream>>>(out, qp, taps, out_n);
    } else {
        dim3 grid(HV / BN, BATCH / BM);        // (64, 8)
        gemm_f32in<<<grid, 256, 0, stream>>>(x, W, out, out_n);
        norm_conv<<<BATCH, 256, 0, stream>>>(out, qp, nullptr, out_n);
    }
}